// Round 9
// baseline (370.062 us; speedup 1.0000x reference)
//
#include <hip/hip_runtime.h>
#include <hip/hip_bf16.h>
#include <hip/hip_fp16.h>

// GCN: x1 = relu(scatter(norm * (X@W1)[src] -> dst) + b1)
//      x2 = relu(scatter(norm * (x1@W2)[src] -> dst) + b2)
//      out = meanpool_by_graph(x2) @ Wlin + blin
// norm factored: out[d] = dis[d]*(sum_s dis[s]*h[s] + dis[d]*h[d]) + b.
// Fusions: {bin_edges ∥ prep_w}, {build_csr ∥ gemm1},
//          {agg_l1 + gemm2} (row-wise GEMM => block-local fusion via LDS),
//          {agg_l2 + pool partial} (register accumulation + rare atomic flush).
constexpr int NN = 100000;   // nodes
constexpr int NE = 1600000;  // edges
constexpr int NG = 512;      // graphs
constexpr int F  = 128;      // feature dim (in == hidden)

constexpr int NB   = 392;    // buckets: node bucket = dst >> 8
constexpr int RCAP = 4608;   // per-bucket region capacity (Poisson(4082) + 8 sigma)
constexpr int CAP  = 32;     // LDS staging entries per bucket
constexpr int BINB = 512;    // bin_edges blocks
constexpr int GEMB = (NN + 127) / 128;  // 128-row blocks (782)
constexpr int F2B  = (NN + 63) / 64;    // fused2 blocks (64 nodes each)

typedef _Float16 f16;
typedef f16 f16x2 __attribute__((ext_vector_type(2)));
typedef f16 f16x4 __attribute__((ext_vector_type(4)));
typedef f16 f16x8 __attribute__((ext_vector_type(8)));
typedef float f32x4 __attribute__((ext_vector_type(4)));
typedef unsigned int u32;
typedef u32 u32x4a __attribute__((ext_vector_type(4), aligned(4)));

// ---------------- K1: bin_edges(0..BINB-1) ∥ prep_w(BINB..) ----------------
__global__ __launch_bounds__(256) void k1_bin_prepw(const int* __restrict__ ei,
                                                    int* __restrict__ gcur,
                                                    u32* __restrict__ binned,
                                                    const float* __restrict__ W1,
                                                    const float* __restrict__ W2,
                                                    f16* __restrict__ WT1,
                                                    f16* __restrict__ WT2) {
    __shared__ u32 stage[NB][CAP];   // 50 KB
    __shared__ int scnt[NB];
    if (blockIdx.x >= BINB) {        // prep_w part
        int idx = (blockIdx.x - BINB) * 256 + threadIdx.x;
        int n = idx >> 7, k = idx & 127;
        WT1[idx] = (f16)W1[k * 128 + n];
        WT2[idx] = (f16)W2[k * 128 + n];
        return;
    }
    for (int b = threadIdx.x; b < NB; b += 256) scnt[b] = 0;
    __syncthreads();
    const int per = NE / BINB;       // 3125
    const int e0 = blockIdx.x * per;
    for (int r = 0; r < per; r += 256) {
        int k = r + threadIdx.x;
        if (k < per) {
            int e = e0 + k;
            int s = __builtin_nontemporal_load(&ei[e]);
            int d = __builtin_nontemporal_load(&ei[NE + e]);
            int b = d >> 8;
            u32 v = ((u32)(d & 255) << 24) | (u32)s;
            int p = atomicAdd(&scnt[b], 1);
            if (p < CAP) stage[b][p] = v;   // overflow P ~ 1e-18
        }
        __syncthreads();
        for (int b2 = threadIdx.x; b2 < NB; b2 += 256) {
            int n = scnt[b2];
            if (n >= 16) {
                int f = n & ~15;
                int base = b2 * RCAP + atomicAdd(&gcur[b2], f);
                const u32x4a* st4 = (const u32x4a*)&stage[b2][0];
                u32x4a* out4 = (u32x4a*)&binned[base];
                for (int j = 0; j < (f >> 2); j++) out4[j] = st4[j];
                for (int j = 0; j < n - f; j++) stage[b2][j] = stage[b2][f + j];
                scnt[b2] = n - f;
            }
        }
        __syncthreads();
    }
    for (int b2 = threadIdx.x; b2 < NB; b2 += 256) {
        int n = scnt[b2];
        if (n > 0) {
            int base = b2 * RCAP + atomicAdd(&gcur[b2], n);
            for (int j = 0; j < n; j++) binned[base + j] = stage[b2][j];
        }
    }
}

// ---------------- scan bucket counts -> bucket bases ----------------
__global__ void scan_buckets(const int* __restrict__ gcur, int* __restrict__ bucketBase,
                             int* __restrict__ offs) {
    __shared__ int tmp[512];
    int t = threadIdx.x;
    int c = (t < NB) ? gcur[t] : 0;
    tmp[t] = c;
    __syncthreads();
    for (int d = 1; d < 512; d <<= 1) {
        int x = (t >= d) ? tmp[t - d] : 0;
        __syncthreads();
        tmp[t] += x;
        __syncthreads();
    }
    if (t < NB) bucketBase[t] = tmp[t] - c;
    if (t == 0) offs[NN] = NE;
}

// ---------------- gemm core: H rows = (X @ W) [* dis] ----------------
template<bool IN_HALF, bool SCALE>
__device__ __forceinline__ void gemm_body(int bid, int tid,
                                          const void* __restrict__ Xv,
                                          const f16* __restrict__ WT,  // [n][k]
                                          const float* __restrict__ dis,
                                          f16* __restrict__ H, int M) {
    const int wid = tid >> 6;
    const int lane = tid & 63;
    const int row0 = bid * 128;
    const int wrow = wid * 32;
    const int lr = lane & 15;
    const int lk = (lane >> 4) * 8;
    f32x4 acc[2][8] = {};
    #pragma unroll
    for (int ks = 0; ks < 4; ks++) {
        f16x8 a[2], b[8];
        #pragma unroll
        for (int mf = 0; mf < 2; mf++) {
            int row = row0 + wrow + mf * 16 + lr;
            row = row < M ? row : M - 1;
            if (IN_HALF) {
                a[mf] = *(const f16x8*)((const f16*)Xv + (size_t)row * 128 + ks * 32 + lk);
            } else {
                const float* Xf = (const float*)Xv + (size_t)row * 128 + ks * 32 + lk;
                float4 v0 = *(const float4*)Xf;
                float4 v1 = *(const float4*)(Xf + 4);
                a[mf] = f16x8{(f16)v0.x, (f16)v0.y, (f16)v0.z, (f16)v0.w,
                              (f16)v1.x, (f16)v1.y, (f16)v1.z, (f16)v1.w};
            }
        }
        #pragma unroll
        for (int nf = 0; nf < 8; nf++)
            b[nf] = *(const f16x8*)(WT + (size_t)(nf * 16 + lr) * 128 + ks * 32 + lk);
        #pragma unroll
        for (int mf = 0; mf < 2; mf++)
            #pragma unroll
            for (int nf = 0; nf < 8; nf++)
                acc[mf][nf] = __builtin_amdgcn_mfma_f32_16x16x32_f16(a[mf], b[nf], acc[mf][nf], 0, 0, 0);
    }
    const int crow = (lane >> 4) * 4;
    #pragma unroll
    for (int mf = 0; mf < 2; mf++) {
        #pragma unroll
        for (int reg = 0; reg < 4; reg++) {
            int row = row0 + wrow + mf * 16 + crow + reg;
            if (row < M) {
                float sc = SCALE ? dis[row] : 1.0f;
                #pragma unroll
                for (int nf = 0; nf < 8; nf++)
                    H[(size_t)row * 128 + nf * 16 + lr] = (f16)(acc[mf][nf][reg] * sc);
            }
        }
    }
}

// ---------------- K3: build_csr(0..NB-1) ∥ gemm1(NB..) [unscaled] ----------------
__global__ __launch_bounds__(256) void k3_csr_gemm1(const u32* __restrict__ binned,
                                                    const int* __restrict__ gcur,
                                                    const int* __restrict__ bucketBase,
                                                    int* __restrict__ offs,
                                                    float* __restrict__ dis,
                                                    int* __restrict__ csr_src,
                                                    const float* __restrict__ X,
                                                    const f16* __restrict__ WT1,
                                                    f16* __restrict__ H) {
    __shared__ u32 ed[RCAP];
    __shared__ u32 lcsr[RCAP];
    __shared__ int hist[256];
    __shared__ int loff[256];
    __shared__ int lcur[256];
    if (blockIdx.x >= NB) {
        gemm_body<false, false>(blockIdx.x - NB, threadIdx.x, X, WT1, nullptr, H, NN);
        return;
    }
    const int b = blockIdx.x;
    int cnt = gcur[b];
    if (cnt > RCAP) cnt = RCAP;
    const int gbase = bucketBase[b];
    const int t = threadIdx.x;
    hist[t] = 0;
    __syncthreads();
    for (int j = t; j < cnt; j += 256) {
        u32 v = __builtin_nontemporal_load(&binned[(size_t)b * RCAP + j]);
        ed[j] = v;
        atomicAdd(&hist[v >> 24], 1);
    }
    __syncthreads();
    int h = hist[t];
    loff[t] = h;
    __syncthreads();
    for (int d = 1; d < 256; d <<= 1) {
        int x = (t >= d) ? loff[t - d] : 0;
        __syncthreads();
        loff[t] += x;
        __syncthreads();
    }
    int excl = loff[t] - h;
    lcur[t] = excl;
    int node = (b << 8) + t;
    if (node < NN) {
        offs[node] = gbase + excl;
        dis[node] = rsqrtf((float)(h + 1));   // +1 self-loop
    }
    __syncthreads();
    for (int j = t; j < cnt; j += 256) {
        u32 v = ed[j];
        int p = atomicAdd(&lcur[v >> 24], 1);
        lcsr[p] = v & 0x1FFFFu;
    }
    __syncthreads();
    for (int j = t; j < cnt; j += 256) csr_src[gbase + j] = (int)lcsr[j];
}

// ---------------- gather cores (R5 loop shape: unroll-2, plain loads) ----------------
__device__ __forceinline__ void gather_rows_scaled(const f16* __restrict__ h, int i,
                                                   const int* __restrict__ offs,
                                                   const int* __restrict__ csr_src,
                                                   const float* __restrict__ dis,
                                                   int q, int r, float acc[8]) {
    if (q == 0) {  // self-loop: dis[i]*h[i]
        f16x8 v = *(const f16x8*)(h + (size_t)i * F + r * 8);
        float di = dis[i];
        #pragma unroll
        for (int j = 0; j < 8; j++) acc[j] = (float)v[j] * di;
    }
    const int s = offs[i], e = offs[i + 1];
    int t = s + q;
    for (; t + 4 < e; t += 8) {
        int sr0 = csr_src[t];
        int sr1 = csr_src[t + 4];
        float d0 = dis[sr0], d1 = dis[sr1];
        f16x8 v0 = *(const f16x8*)(h + (size_t)sr0 * F + r * 8);
        f16x8 v1 = *(const f16x8*)(h + (size_t)sr1 * F + r * 8);
        #pragma unroll
        for (int j = 0; j < 8; j++)
            acc[j] += (float)v0[j] * d0 + (float)v1[j] * d1;
    }
    if (t < e) {
        int sr = csr_src[t];
        float d0 = dis[sr];
        f16x8 v = *(const f16x8*)(h + (size_t)sr * F + r * 8);
        #pragma unroll
        for (int j = 0; j < 8; j++) acc[j] += (float)v[j] * d0;
    }
    #pragma unroll
    for (int j = 0; j < 8; j++) {
        acc[j] += __shfl_xor(acc[j], 16);
        acc[j] += __shfl_xor(acc[j], 32);
    }
}

__device__ __forceinline__ void gather_rows(const f16* __restrict__ h, int i,
                                            const int* __restrict__ offs,
                                            const int* __restrict__ csr_src,
                                            int q, int r, float acc[8]) {
    if (q == 0) {
        f16x8 v = *(const f16x8*)(h + (size_t)i * F + r * 8);
        #pragma unroll
        for (int j = 0; j < 8; j++) acc[j] = (float)v[j];
    }
    const int s = offs[i], e = offs[i + 1];
    int t = s + q;
    for (; t + 4 < e; t += 8) {
        int sr0 = csr_src[t];
        int sr1 = csr_src[t + 4];
        f16x8 v0 = *(const f16x8*)(h + (size_t)sr0 * F + r * 8);
        f16x8 v1 = *(const f16x8*)(h + (size_t)sr1 * F + r * 8);
        #pragma unroll
        for (int j = 0; j < 8; j++) acc[j] += (float)v0[j] + (float)v1[j];
    }
    if (t < e) {
        int sr = csr_src[t];
        f16x8 v = *(const f16x8*)(h + (size_t)sr * F + r * 8);
        #pragma unroll
        for (int j = 0; j < 8; j++) acc[j] += (float)v[j];
    }
    #pragma unroll
    for (int j = 0; j < 8; j++) {
        acc[j] += __shfl_xor(acc[j], 16);
        acc[j] += __shfl_xor(acc[j], 32);
    }
}

// ---------------- fused1: agg_l1 (gather h1, scaled) -> x1 in LDS -> @W2 -> h2' ----------------
// 4 waves x 32 nodes; wave-private LDS tile (no barriers). Row stride 136 f16
// (272 B: 2-way bank aliasing = free, 16 B aligned).
__global__ __launch_bounds__(256) void fused_agg1_gemm2(const f16* __restrict__ h1,
                                                        const int* __restrict__ offs,
                                                        const int* __restrict__ csr_src,
                                                        const float* __restrict__ dis,
                                                        const float* __restrict__ bias,
                                                        const f16* __restrict__ WT2,
                                                        f16* __restrict__ H, int n) {
    __shared__ f16 sX[4][32 * 136];   // 34.8 KB
    const int wid = threadIdx.x >> 6;
    const int lane = threadIdx.x & 63;
    const int q = lane >> 4;
    const int r = lane & 15;
    const int row0 = blockIdx.x * 128 + wid * 32;
    const float4* b4 = (const float4*)bias;
    float4 bb0 = b4[r * 2], bb1 = b4[r * 2 + 1];
    float bb[8] = {bb0.x, bb0.y, bb0.z, bb0.w, bb1.x, bb1.y, bb1.z, bb1.w};
    for (int m = 0; m < 32; m++) {
        int i = row0 + m;
        i = i < n ? i : n - 1;   // clamp: harmless extra work, stores guarded later
        float acc[8] = {};
        gather_rows_scaled(h1, i, offs, csr_src, dis, q, r, acc);
        if (q == 0) {
            float di = dis[i];
            f16x8 o;
            #pragma unroll
            for (int j = 0; j < 8; j++) {
                float v = fmaf(acc[j], di, bb[j]);
                o[j] = (f16)(v > 0.f ? v : 0.f);
            }
            *(f16x8*)&sX[wid][m * 136 + r * 8] = o;   // ds_write_b128
        }
    }
    // x1 tile ready (wave-private; compiler inserts lgkmcnt) -> MFMA with WT2
    const int lk = (lane >> 4) * 8;
    f32x4 acc2[2][8] = {};
    #pragma unroll
    for (int ks = 0; ks < 4; ks++) {
        f16x8 a[2], b[8];
        #pragma unroll
        for (int mf = 0; mf < 2; mf++)
            a[mf] = *(const f16x8*)&sX[wid][(mf * 16 + r) * 136 + ks * 32 + lk];
        #pragma unroll
        for (int nf = 0; nf < 8; nf++)
            b[nf] = *(const f16x8*)(WT2 + (size_t)(nf * 16 + r) * 128 + ks * 32 + lk);
        #pragma unroll
        for (int mf = 0; mf < 2; mf++)
            #pragma unroll
            for (int nf = 0; nf < 8; nf++)
                acc2[mf][nf] = __builtin_amdgcn_mfma_f32_16x16x32_f16(a[mf], b[nf], acc2[mf][nf], 0, 0, 0);
    }
    const int crow = (lane >> 4) * 4;
    #pragma unroll
    for (int mf = 0; mf < 2; mf++) {
        #pragma unroll
        for (int reg = 0; reg < 4; reg++) {
            int row = row0 + mf * 16 + crow + reg;
            if (row < n) {
                float sc = dis[row];
                #pragma unroll
                for (int nf = 0; nf < 8; nf++)
                    H[(size_t)row * 128 + nf * 16 + r] = (f16)(acc2[mf][nf][reg] * sc);
            }
        }
    }
}

// ---------------- fused2: agg_l2 (gather h2', plain) + mean-pool partial ----------------
// 4 waves x 16 consecutive nodes; per-lane register row accumulator, atomic
// flush to partial[g][F] on graph boundary (batch sorted => ~1 flush/wave).
__global__ __launch_bounds__(256) void fused_agg2_pool(const f16* __restrict__ h2,
                                                       const int* __restrict__ offs,
                                                       const int* __restrict__ csr_src,
                                                       const float* __restrict__ dis,
                                                       const float* __restrict__ bias,
                                                       const int* __restrict__ batch,
                                                       float* __restrict__ partial, int n) {
    const int wid = threadIdx.x >> 6;
    const int lane = threadIdx.x & 63;
    const int q = lane >> 4;
    const int r = lane & 15;
    const int base = blockIdx.x * 64 + wid * 16;
    if (base >= n) return;
    const float4* b4 = (const float4*)bias;
    float4 bb0 = b4[r * 2], bb1 = b4[r * 2 + 1];
    float bb[8] = {bb0.x, bb0.y, bb0.z, bb0.w, bb1.x, bb1.y, bb1.z, bb1.w};
    float pacc[8] = {};
    int cur_g = -1;
    for (int m = 0; m < 16; m++) {
        int i = base + m;
        if (i >= n) break;
        float acc[8] = {};
        gather_rows(h2, i, offs, csr_src, q, r, acc);
        int g = batch[i];             // wave-uniform
        if (g != cur_g) {
            if (cur_g >= 0 && q == 0) {
                #pragma unroll
                for (int j = 0; j < 8; j++)
                    atomicAdd(&partial[(size_t)cur_g * F + r * 8 + j], pacc[j]);
            }
            #pragma unroll
            for (int j = 0; j < 8; j++) pacc[j] = 0.f;
            cur_g = g;
        }
        float di = dis[i];
        #pragma unroll
        for (int j = 0; j < 8; j++) {
            float v = fmaf(acc[j], di, bb[j]);
            pacc[j] += v > 0.f ? v : 0.f;   // all quarters identical; flush q==0 only
        }
    }
    if (cur_g >= 0 && q == 0) {
        #pragma unroll
        for (int j = 0; j < 8; j++)
            atomicAdd(&partial[(size_t)cur_g * F + r * 8 + j], pacc[j]);
    }
}

// ---------------- final: mean + linear head ----------------
__global__ __launch_bounds__(128) void pool_final(const float* __restrict__ partial,
                                                  const int* __restrict__ batch,
                                                  const float* __restrict__ Wlin,
                                                  const float* __restrict__ blin,
                                                  float* __restrict__ out, int n) {
    int g = blockIdx.x;
    int f = threadIdx.x;
    __shared__ int se[2];
    if (threadIdx.x < 2) {
        int target = g + threadIdx.x;
        int lo = 0, hi = n;
        while (lo < hi) {
            int mid = (lo + hi) >> 1;
            if (batch[mid] < target) lo = mid + 1; else hi = mid;
        }
        se[threadIdx.x] = lo;
    }
    __syncthreads();
    int s = se[0], e = se[1];
    float cnt = (float)((e - s) > 0 ? (e - s) : 1);
    float p = partial[(size_t)g * F + f] / cnt;
    float v0 = p * Wlin[f * 2 + 0];
    float v1 = p * Wlin[f * 2 + 1];
    #pragma unroll
    for (int o = 32; o > 0; o >>= 1) {
        v0 += __shfl_xor(v0, o);
        v1 += __shfl_xor(v1, o);
    }
    __shared__ float red[4];
    int wid = threadIdx.x >> 6;
    if ((threadIdx.x & 63) == 0) { red[wid * 2] = v0; red[wid * 2 + 1] = v1; }
    __syncthreads();
    if (threadIdx.x == 0) {
        out[g * 2 + 0] = red[0] + red[2] + blin[0];
        out[g * 2 + 1] = red[1] + red[3] + blin[1];
    }
}

extern "C" void kernel_launch(void* const* d_in, const int* in_sizes, int n_in,
                              void* d_out, int out_size, void* d_ws, size_t ws_size,
                              hipStream_t stream) {
    const float* X     = (const float*)d_in[0];
    const int*   ei    = (const int*)d_in[1];
    const int*   batch = (const int*)d_in[2];
    const float* W1    = (const float*)d_in[3];
    const float* b1    = (const float*)d_in[4];
    const float* W2    = (const float*)d_in[5];
    const float* b2    = (const float*)d_in[6];
    const float* Wlin  = (const float*)d_in[7];
    const float* blin  = (const float*)d_in[8];
    float* out = (float*)d_out;

    char* p = (char*)d_ws;
    auto alloc = [&](size_t bytes) -> char* {
        char* r = p;
        p += (bytes + 255) & ~size_t(255);
        return r;
    };
    int*   gcur       = (int*)alloc((size_t)NB * 4);
    int*   bucketBase = (int*)alloc((size_t)NB * 4);
    int*   offs       = (int*)alloc((size_t)(NN + 1) * 4);
    float* dis        = (float*)alloc((size_t)NN * 4);
    u32*   binned     = (u32*)alloc((size_t)NB * RCAP * 4);
    int*   csr_src    = (int*)alloc((size_t)NE * 4);
    f16*   WT1        = (f16*)alloc((size_t)128 * 128 * 2);
    f16*   WT2        = (f16*)alloc((size_t)128 * 128 * 2);
    f16*   bufA       = (f16*)alloc((size_t)NN * F * 2);   // h1 (unscaled)
    f16*   bufC       = (f16*)alloc((size_t)NN * F * 2);   // h2' (dis-scaled)
    float* partial    = (float*)alloc((size_t)NG * F * 4);

    hipMemsetAsync(gcur, 0, (size_t)NB * 4, stream);
    hipMemsetAsync(partial, 0, (size_t)NG * F * 4, stream);

    k1_bin_prepw<<<BINB + 64, 256, 0, stream>>>(ei, gcur, binned, W1, W2, WT1, WT2);
    scan_buckets<<<1, 512, 0, stream>>>(gcur, bucketBase, offs);
    k3_csr_gemm1<<<NB + GEMB, 256, 0, stream>>>(binned, gcur, bucketBase, offs, dis,
                                                csr_src, X, WT1, bufA);
    fused_agg1_gemm2<<<GEMB, 256, 0, stream>>>(bufA, offs, csr_src, dis, b1, WT2, bufC, NN);
    fused_agg2_pool<<<F2B, 256, 0, stream>>>(bufC, offs, csr_src, dis, b2, batch, partial, NN);
    pool_final<<<NG, 128, 0, stream>>>(partial, batch, Wlin, blin, out, NN);
}

// Round 10
// 252.285 us; speedup vs baseline: 1.4668x; 1.4668x over previous
//
#include <hip/hip_runtime.h>
#include <hip/hip_bf16.h>
#include <hip/hip_fp16.h>

// GCN: x1 = relu(scatter(norm * (X@W1)[src] -> dst) + b1)
//      x2 = relu(scatter(norm * (x1@W2)[src] -> dst) + b2)
//      out = meanpool_by_graph(x2) @ Wlin + blin
// norm factored: out[d] = dis[d]*(sum_s dis[s]*h[s] + dis[d]*h[d]) + b.
// R8 structure (proven 263us): separate high-TLP gather kernels; co-scheduled
// {bin_edges ∥ prep_w} and {build_csr ∥ gemm1}; scan folded into build_csr.
constexpr int NN = 100000;   // nodes
constexpr int NE = 1600000;  // edges
constexpr int NG = 512;      // graphs
constexpr int F  = 128;      // feature dim (in == hidden)

constexpr int NB   = 392;    // buckets: node bucket = dst >> 8
constexpr int RCAP = 4608;   // per-bucket region capacity (Poisson(4082) + 8 sigma)
constexpr int CAP  = 32;     // LDS staging entries per bucket
constexpr int NCH  = 8;      // pooling chunks per graph
constexpr int BINB = 512;    // bin_edges blocks
constexpr int GEMB = (NN + 127) / 128;  // 128-row gemm blocks (782)

typedef _Float16 f16;
typedef f16 f16x2 __attribute__((ext_vector_type(2)));
typedef f16 f16x4 __attribute__((ext_vector_type(4)));
typedef f16 f16x8 __attribute__((ext_vector_type(8)));
typedef float f32x4 __attribute__((ext_vector_type(4)));
typedef unsigned int u32;
typedef u32 u32x4a __attribute__((ext_vector_type(4), aligned(4)));

// ---------------- K1: bin_edges(0..BINB-1) ∥ prep_w(BINB..) ----------------
__global__ __launch_bounds__(256) void k1_bin_prepw(const int* __restrict__ ei,
                                                    int* __restrict__ gcur,
                                                    u32* __restrict__ binned,
                                                    const float* __restrict__ W1,
                                                    const float* __restrict__ W2,
                                                    f16* __restrict__ WT1,
                                                    f16* __restrict__ WT2) {
    __shared__ u32 stage[NB][CAP];   // 50 KB
    __shared__ int scnt[NB];
    if (blockIdx.x >= BINB) {        // prep_w part
        int idx = (blockIdx.x - BINB) * 256 + threadIdx.x;
        int n = idx >> 7, k = idx & 127;
        WT1[idx] = (f16)W1[k * 128 + n];
        WT2[idx] = (f16)W2[k * 128 + n];
        return;
    }
    for (int b = threadIdx.x; b < NB; b += 256) scnt[b] = 0;
    __syncthreads();
    const int per = NE / BINB;       // 3125
    const int e0 = blockIdx.x * per;
    for (int r = 0; r < per; r += 256) {
        int k = r + threadIdx.x;
        if (k < per) {
            int e = e0 + k;
            int s = __builtin_nontemporal_load(&ei[e]);
            int d = __builtin_nontemporal_load(&ei[NE + e]);
            int b = d >> 8;
            u32 v = ((u32)(d & 255) << 24) | (u32)s;
            int p = atomicAdd(&scnt[b], 1);
            if (p < CAP) stage[b][p] = v;   // overflow P ~ 1e-18
        }
        __syncthreads();
        for (int b2 = threadIdx.x; b2 < NB; b2 += 256) {
            int n = scnt[b2];
            if (n >= 16) {
                int f = n & ~15;
                int base = b2 * RCAP + atomicAdd(&gcur[b2], f);
                const u32x4a* st4 = (const u32x4a*)&stage[b2][0];
                u32x4a* out4 = (u32x4a*)&binned[base];
                for (int j = 0; j < (f >> 2); j++) out4[j] = st4[j];
                for (int j = 0; j < n - f; j++) stage[b2][j] = stage[b2][f + j];
                scnt[b2] = n - f;
            }
        }
        __syncthreads();
    }
    for (int b2 = threadIdx.x; b2 < NB; b2 += 256) {
        int n = scnt[b2];
        if (n > 0) {
            int base = b2 * RCAP + atomicAdd(&gcur[b2], n);
            for (int j = 0; j < n; j++) binned[base + j] = stage[b2][j];
        }
    }
}

// ---------------- gemm core: H rows = (X @ W) [* dis] ----------------
template<bool IN_HALF, bool SCALE>
__device__ __forceinline__ void gemm_body(int bid, int tid,
                                          const void* __restrict__ Xv,
                                          const f16* __restrict__ WT,  // [n][k]
                                          const float* __restrict__ dis,
                                          f16* __restrict__ H, int M) {
    const int wid = tid >> 6;
    const int lane = tid & 63;
    const int row0 = bid * 128;
    const int wrow = wid * 32;
    const int lr = lane & 15;
    const int lk = (lane >> 4) * 8;
    f32x4 acc[2][8] = {};
    #pragma unroll
    for (int ks = 0; ks < 4; ks++) {
        f16x8 a[2], b[8];
        #pragma unroll
        for (int mf = 0; mf < 2; mf++) {
            int row = row0 + wrow + mf * 16 + lr;
            row = row < M ? row : M - 1;
            if (IN_HALF) {
                a[mf] = *(const f16x8*)((const f16*)Xv + (size_t)row * 128 + ks * 32 + lk);
            } else {
                const float* Xf = (const float*)Xv + (size_t)row * 128 + ks * 32 + lk;
                float4 v0 = *(const float4*)Xf;
                float4 v1 = *(const float4*)(Xf + 4);
                a[mf] = f16x8{(f16)v0.x, (f16)v0.y, (f16)v0.z, (f16)v0.w,
                              (f16)v1.x, (f16)v1.y, (f16)v1.z, (f16)v1.w};
            }
        }
        #pragma unroll
        for (int nf = 0; nf < 8; nf++)
            b[nf] = *(const f16x8*)(WT + (size_t)(nf * 16 + lr) * 128 + ks * 32 + lk);
        #pragma unroll
        for (int mf = 0; mf < 2; mf++)
            #pragma unroll
            for (int nf = 0; nf < 8; nf++)
                acc[mf][nf] = __builtin_amdgcn_mfma_f32_16x16x32_f16(a[mf], b[nf], acc[mf][nf], 0, 0, 0);
    }
    // C layout: col = lane&15, row = (lane>>4)*4 + reg
    const int crow = (lane >> 4) * 4;
    #pragma unroll
    for (int mf = 0; mf < 2; mf++) {
        #pragma unroll
        for (int reg = 0; reg < 4; reg++) {
            int row = row0 + wrow + mf * 16 + crow + reg;
            if (row < M) {
                float sc = SCALE ? dis[row] : 1.0f;
                #pragma unroll
                for (int nf = 0; nf < 8; nf++)
                    H[(size_t)row * 128 + nf * 16 + lr] = (f16)(acc[mf][nf][reg] * sc);
            }
        }
    }
}

// ---------------- K2: build_csr(0..NB-1, self-scan) ∥ gemm1(NB..) ----------------
__global__ __launch_bounds__(256) void k2_csr_gemm1(const u32* __restrict__ binned,
                                                    const int* __restrict__ gcur,
                                                    int* __restrict__ offs,
                                                    float* __restrict__ dis,
                                                    int* __restrict__ csr_src,
                                                    const float* __restrict__ X,
                                                    const f16* __restrict__ WT1,
                                                    f16* __restrict__ H) {
    __shared__ u32 ed[RCAP];     // 18.4 KB
    __shared__ u32 lcsr[RCAP];   // 18.4 KB
    __shared__ int hist[256];
    __shared__ int loff[256];
    __shared__ int lcur[256];
    if (blockIdx.x >= NB) {      // gemm1 (fp32 input, unscaled output)
        gemm_body<false, false>(blockIdx.x - NB, threadIdx.x, X, WT1, nullptr, H, NN);
        return;
    }
    const int b = blockIdx.x;
    const int t = threadIdx.x;
    // self-scan: gbase = sum of gcur[0..b)
    {
        int c0 = (t < b) ? gcur[t] : 0;                       // t < 256
        int c1 = (t + 256 < b) ? gcur[t + 256] : 0;           // covers NB=392
        loff[t] = c0 + c1;
        __syncthreads();
        for (int d = 128; d > 0; d >>= 1) {
            if (t < d) loff[t] += loff[t + d];
            __syncthreads();
        }
    }
    const int gbase = loff[0];
    __syncthreads();
    int cnt = gcur[b];
    if (cnt > RCAP) cnt = RCAP;
    hist[t] = 0;
    if (b == 0 && t == 0) offs[NN] = NE;
    __syncthreads();
    for (int j = t; j < cnt; j += 256) {
        u32 v = __builtin_nontemporal_load(&binned[(size_t)b * RCAP + j]);
        ed[j] = v;
        atomicAdd(&hist[v >> 24], 1);
    }
    __syncthreads();
    int h = hist[t];
    loff[t] = h;
    __syncthreads();
    for (int d = 1; d < 256; d <<= 1) {
        int x = (t >= d) ? loff[t - d] : 0;
        __syncthreads();
        loff[t] += x;
        __syncthreads();
    }
    int excl = loff[t] - h;
    lcur[t] = excl;
    int node = (b << 8) + t;
    if (node < NN) {
        offs[node] = gbase + excl;
        dis[node] = rsqrtf((float)(h + 1));   // +1 self-loop
    }
    __syncthreads();
    for (int j = t; j < cnt; j += 256) {
        u32 v = ed[j];
        int p = atomicAdd(&lcur[v >> 24], 1);
        lcsr[p] = v & 0x1FFFFu;
    }
    __syncthreads();
    for (int j = t; j < cnt; j += 256) csr_src[gbase + j] = (int)lcsr[j];
}

// ---------------- gather cores (R5 loop shape: unroll-2, plain loads) ----------------
__device__ __forceinline__ void gather_rows_scaled(const f16* __restrict__ h, int i,
                                                   const int* __restrict__ offs,
                                                   const int* __restrict__ csr_src,
                                                   const float* __restrict__ dis,
                                                   int q, int r, float acc[8]) {
    if (q == 0) {  // self-loop: dis[i]*h[i]
        f16x8 v = *(const f16x8*)(h + (size_t)i * F + r * 8);
        float di = dis[i];
        #pragma unroll
        for (int j = 0; j < 8; j++) acc[j] = (float)v[j] * di;
    }
    const int s = offs[i], e = offs[i + 1];
    int t = s + q;
    for (; t + 4 < e; t += 8) {
        int sr0 = csr_src[t];
        int sr1 = csr_src[t + 4];
        float d0 = dis[sr0], d1 = dis[sr1];
        f16x8 v0 = *(const f16x8*)(h + (size_t)sr0 * F + r * 8);
        f16x8 v1 = *(const f16x8*)(h + (size_t)sr1 * F + r * 8);
        #pragma unroll
        for (int j = 0; j < 8; j++)
            acc[j] += (float)v0[j] * d0 + (float)v1[j] * d1;
    }
    if (t < e) {
        int sr = csr_src[t];
        float d0 = dis[sr];
        f16x8 v = *(const f16x8*)(h + (size_t)sr * F + r * 8);
        #pragma unroll
        for (int j = 0; j < 8; j++) acc[j] += (float)v[j] * d0;
    }
    #pragma unroll
    for (int j = 0; j < 8; j++) {
        acc[j] += __shfl_xor(acc[j], 16);
        acc[j] += __shfl_xor(acc[j], 32);
    }
}

__device__ __forceinline__ void gather_rows(const f16* __restrict__ h, int i,
                                            const int* __restrict__ offs,
                                            const int* __restrict__ csr_src,
                                            int q, int r, float acc[8]) {
    if (q == 0) {
        f16x8 v = *(const f16x8*)(h + (size_t)i * F + r * 8);
        #pragma unroll
        for (int j = 0; j < 8; j++) acc[j] = (float)v[j];
    }
    const int s = offs[i], e = offs[i + 1];
    int t = s + q;
    for (; t + 4 < e; t += 8) {
        int sr0 = csr_src[t];
        int sr1 = csr_src[t + 4];
        f16x8 v0 = *(const f16x8*)(h + (size_t)sr0 * F + r * 8);
        f16x8 v1 = *(const f16x8*)(h + (size_t)sr1 * F + r * 8);
        #pragma unroll
        for (int j = 0; j < 8; j++) acc[j] += (float)v0[j] + (float)v1[j];
    }
    if (t < e) {
        int sr = csr_src[t];
        f16x8 v = *(const f16x8*)(h + (size_t)sr * F + r * 8);
        #pragma unroll
        for (int j = 0; j < 8; j++) acc[j] += (float)v[j];
    }
    #pragma unroll
    for (int j = 0; j < 8; j++) {
        acc[j] += __shfl_xor(acc[j], 16);
        acc[j] += __shfl_xor(acc[j], 32);
    }
}

// ---------------- aggregate1: per-src scaled gather + bias + relu -> fp16 ----------------
__global__ __launch_bounds__(256) void aggregate_l1(const f16* __restrict__ h,
                                                    const int* __restrict__ offs,
                                                    const int* __restrict__ csr_src,
                                                    const float* __restrict__ dis,
                                                    const float* __restrict__ bias,
                                                    f16* __restrict__ out, int n) {
    int i = blockIdx.x * 4 + (threadIdx.x >> 6);
    if (i >= n) return;
    const int lane = threadIdx.x & 63;
    const int q = lane >> 4;
    const int r = lane & 15;
    float acc[8] = {};
    gather_rows_scaled(h, i, offs, csr_src, dis, q, r, acc);
    if (q == 0) {
        float di = dis[i];
        const float4* b4 = (const float4*)bias;
        float4 bb0 = b4[r * 2], bb1 = b4[r * 2 + 1];
        float bb[8] = {bb0.x, bb0.y, bb0.z, bb0.w, bb1.x, bb1.y, bb1.z, bb1.w};
        f16x8 o;
        #pragma unroll
        for (int j = 0; j < 8; j++) {
            float v = fmaf(acc[j], di, bb[j]);
            o[j] = (f16)(v > 0.f ? v : 0.f);
        }
        *(f16x8*)(out + (size_t)i * F + r * 8) = o;
    }
}

// ---------------- aggregate2: rows pre-scaled by gemm2 epilogue ----------------
__global__ __launch_bounds__(256) void aggregate_l2(const f16* __restrict__ h,
                                                    const int* __restrict__ offs,
                                                    const int* __restrict__ csr_src,
                                                    const float* __restrict__ dis,
                                                    const float* __restrict__ bias,
                                                    f16* __restrict__ out, int n) {
    int i = blockIdx.x * 4 + (threadIdx.x >> 6);
    if (i >= n) return;
    const int lane = threadIdx.x & 63;
    const int q = lane >> 4;
    const int r = lane & 15;
    float acc[8] = {};
    gather_rows(h, i, offs, csr_src, q, r, acc);
    if (q == 0) {
        float di = dis[i];
        const float4* b4 = (const float4*)bias;
        float4 bb0 = b4[r * 2], bb1 = b4[r * 2 + 1];
        float bb[8] = {bb0.x, bb0.y, bb0.z, bb0.w, bb1.x, bb1.y, bb1.z, bb1.w};
        f16x8 o;
        #pragma unroll
        for (int j = 0; j < 8; j++) {
            float v = fmaf(acc[j], di, bb[j]);
            o[j] = (f16)(v > 0.f ? v : 0.f);
        }
        *(f16x8*)(out + (size_t)i * F + r * 8) = o;
    }
}

// ---------------- gemm2 standalone (fp16 input, dis-scaled output) ----------------
__global__ __launch_bounds__(256) void gemm2(const f16* __restrict__ Xh,
                                             const f16* __restrict__ WT,
                                             const float* __restrict__ dis,
                                             f16* __restrict__ H, int M) {
    gemm_body<true, true>(blockIdx.x, threadIdx.x, Xh, WT, dis, H, M);
}

// ---------------- pooling stage 1: 32-way parallel partial sums ----------------
__global__ __launch_bounds__(256) void pool_partial(const f16* __restrict__ x,
                                                    const int* __restrict__ batch,
                                                    float* __restrict__ partial, int n) {
    int g = blockIdx.x;
    __shared__ int se[2];
    if (threadIdx.x < 2) {
        int target = g + threadIdx.x;
        int lo = 0, hi = n;
        while (lo < hi) {
            int mid = (lo + hi) >> 1;
            if (batch[mid] < target) lo = mid + 1; else hi = mid;
        }
        se[threadIdx.x] = lo;
    }
    __syncthreads();
    int s = se[0], e = se[1];
    int wid = threadIdx.x >> 6, lane = threadIdx.x & 63;
    int slot = blockIdx.y * 4 + wid;  // 0..31
    float a0 = 0.f, a1 = 0.f;
    const f16x2* x2 = (const f16x2*)x;
    for (int i = s + slot; i < e; i += 4 * NCH) {
        f16x2 v = x2[(size_t)i * 64 + lane];
        a0 += (float)v[0];
        a1 += (float)v[1];
    }
    __shared__ float red[4][128];
    red[wid][lane * 2] = a0;
    red[wid][lane * 2 + 1] = a1;
    __syncthreads();
    if (wid == 0) {
        float s0 = red[0][lane * 2] + red[1][lane * 2] + red[2][lane * 2] + red[3][lane * 2];
        float s1 = red[0][lane * 2 + 1] + red[1][lane * 2 + 1] + red[2][lane * 2 + 1] + red[3][lane * 2 + 1];
        float2* pp = (float2*)&partial[((size_t)g * NCH + blockIdx.y) * F];
        pp[lane] = make_float2(s0, s1);
    }
}

// ---------------- pooling stage 2: final reduce + linear head ----------------
__global__ __launch_bounds__(128) void pool_final(const float* __restrict__ partial,
                                                  const int* __restrict__ batch,
                                                  const float* __restrict__ Wlin,
                                                  const float* __restrict__ blin,
                                                  float* __restrict__ out, int n) {
    int g = blockIdx.x;
    int f = threadIdx.x;
    __shared__ int se[2];
    if (threadIdx.x < 2) {
        int target = g + threadIdx.x;
        int lo = 0, hi = n;
        while (lo < hi) {
            int mid = (lo + hi) >> 1;
            if (batch[mid] < target) lo = mid + 1; else hi = mid;
        }
        se[threadIdx.x] = lo;
    }
    __syncthreads();
    int s = se[0], e = se[1];
    float acc = 0.f;
    #pragma unroll
    for (int c = 0; c < NCH; c++) acc += partial[((size_t)g * NCH + c) * F + f];
    float cnt = (float)((e - s) > 0 ? (e - s) : 1);
    float p = acc / cnt;
    float v0 = p * Wlin[f * 2 + 0];
    float v1 = p * Wlin[f * 2 + 1];
    #pragma unroll
    for (int o = 32; o > 0; o >>= 1) {
        v0 += __shfl_xor(v0, o);
        v1 += __shfl_xor(v1, o);
    }
    __shared__ float red[4];
    int wid = threadIdx.x >> 6;
    if ((threadIdx.x & 63) == 0) { red[wid * 2] = v0; red[wid * 2 + 1] = v1; }
    __syncthreads();
    if (threadIdx.x == 0) {
        out[g * 2 + 0] = red[0] + red[2] + blin[0];
        out[g * 2 + 1] = red[1] + red[3] + blin[1];
    }
}

extern "C" void kernel_launch(void* const* d_in, const int* in_sizes, int n_in,
                              void* d_out, int out_size, void* d_ws, size_t ws_size,
                              hipStream_t stream) {
    const float* X     = (const float*)d_in[0];
    const int*   ei    = (const int*)d_in[1];
    const int*   batch = (const int*)d_in[2];
    const float* W1    = (const float*)d_in[3];
    const float* b1    = (const float*)d_in[4];
    const float* W2    = (const float*)d_in[5];
    const float* b2    = (const float*)d_in[6];
    const float* Wlin  = (const float*)d_in[7];
    const float* blin  = (const float*)d_in[8];
    float* out = (float*)d_out;

    char* p = (char*)d_ws;
    auto alloc = [&](size_t bytes) -> char* {
        char* r = p;
        p += (bytes + 255) & ~size_t(255);
        return r;
    };
    int*   gcur       = (int*)alloc((size_t)NB * 4);
    int*   offs       = (int*)alloc((size_t)(NN + 1) * 4);
    float* dis        = (float*)alloc((size_t)NN * 4);
    u32*   binned     = (u32*)alloc((size_t)NB * RCAP * 4);
    int*   csr_src    = (int*)alloc((size_t)NE * 4);
    f16*   WT1        = (f16*)alloc((size_t)128 * 128 * 2);
    f16*   WT2        = (f16*)alloc((size_t)128 * 128 * 2);
    f16*   bufA       = (f16*)alloc((size_t)NN * F * 2);   // h1, then h2'
    f16*   bufB       = (f16*)alloc((size_t)NN * F * 2);   // x1, then x2
    float* partial    = (float*)alloc((size_t)NG * NCH * F * 4);

    hipMemsetAsync(gcur, 0, (size_t)NB * 4, stream);
    k1_bin_prepw<<<BINB + 64, 256, 0, stream>>>(ei, gcur, binned, W1, W2, WT1, WT2);
    k2_csr_gemm1<<<NB + GEMB, 256, 0, stream>>>(binned, gcur, offs, dis, csr_src,
                                                X, WT1, bufA);
    aggregate_l1<<<(NN + 3) / 4, 256, 0, stream>>>(bufA, offs, csr_src, dis, b1, bufB, NN);
    gemm2<<<GEMB, 256, 0, stream>>>(bufB, WT2, dis, bufA, NN);
    aggregate_l2<<<(NN + 3) / 4, 256, 0, stream>>>(bufA, offs, csr_src, dis, b2, bufB, NN);
    pool_partial<<<dim3(NG, NCH), 256, 0, stream>>>(bufB, batch, partial, NN);
    pool_final<<<NG, 128, 0, stream>>>(partial, batch, Wlin, blin, out, NN);
}